// Round 9
// baseline (520.493 us; speedup 1.0000x reference)
//
#include <hip/hip_runtime.h>

#define NL 16384          // row length
#define NB 64             // rows = blocks
#define NT 512            // threads per block
#define NC (NL / NT)      // 32 elements per thread
#define N_ITER 12
#define N_IMFS 6

#pragma clang fp contract(off)   // everything unfused EXCEPT the explicit fmaf

#define HSZ (NL + (NL >> 5))   // 16896 floats, swizzled row storage

__device__ __forceinline__ int physi(int i) { return i + (i >> 5); }

// block-wide f64 sum; valid result only in thread 0
__device__ __forceinline__ double blk_reduce_d(double v, double* tmp) {
  #pragma unroll
  for (int o = 32; o > 0; o >>= 1) v += __shfl_down(v, o, 64);
  int lane = threadIdx.x & 63, w = threadIdx.x >> 6;
  __syncthreads();                 // protect tmp reuse across calls
  if (lane == 0) tmp[w] = v;
  __syncthreads();
  double s = 0.0;
  if (threadIdx.x == 0) {
    #pragma unroll
    for (int i = 0; i < NT / 64; i++) s += tmp[i];
  }
  return s;
}

// Ground-truth model: XLA-CPU f32 execution of the JAX reference, fast-math
// contraction ON -> the interp `vl + frac*(vr-vl)` is a single-rounding FMA.
// Everything else strict f32 (R1 semantics); machinery bit-certified in R5.
__global__ __launch_bounds__(NT, 2) void emd_main(
    const float* __restrict__ x, float* __restrict__ out,
    unsigned* cnt, double* sdsl, double* flsl) {
  __shared__ float h[HSZ];                        // 67584 B
  __shared__ int sLU[NT], sLL[NT], sNU[NT], sNL[NT], sCU[NT], sCL[NT];
  __shared__ float sMx[NT], sMn[NT];
  __shared__ double tmp8[NT / 64];
  __shared__ int sFlag;

  const int t = threadIdx.x;
  const int row = blockIdx.x;
  const int base = t * NC;
  const float* xr = x + (size_t)row * NL;
  float* res = out + (size_t)N_IMFS * NB * NL + (size_t)row * NL;

  // init: h = x row (f32 LDS, swizzled); res slab of d_out = x
  for (int m = 0; m < NC; m++) {
    int i = m * NT + t;
    float v = xr[i];
    h[physi(i)] = v;
    res[i] = v;
  }
  __syncthreads();

  unsigned ep = 0;
  bool done = false;

  for (int k = 0; k < N_IMFS; k++) {
    float* outk = out + (size_t)k * NB * NL + (size_t)row * NL;
    if (done) {  // globally-uniform: all blocks skip together (no barriers)
      for (int m = 0; m < NC; m++) outk[m * NT + t] = 0.0f;
      continue;
    }

    // ---------------- sifting ----------------
    for (int it = 0; it < N_ITER; it++) {
      // pass A: forward walk (prev-peak idx, peak counts, chunk max/min)
      int lmU = -1, lmL = -1, cU = 0, cL = 0;
      float rmx = -3.402823466e38f, rmn = 3.402823466e38f;
      for (int j = 0; j < NC; j++) {
        int i = base + j;
        float hc = h[physi(i)];
        if (i > 0 && i + 1 < NL) {
          float hm = h[physi(i - 1)], hp = h[physi(i + 1)];
          if (hm < hc && hc > hp) { lmU = i; cU++; }
          if (hm > hc && hc < hp) { lmL = i; cL++; }
        }
        rmx = fmaxf(rmx, hc);
        rmn = fminf(rmn, hc);
      }
      // pass B: backward walk (next-peak idx per element, packed in registers)
      unsigned nreg[NC];
      int nUc = NL, nLc = NL;
      for (int j = NC - 1; j >= 0; j--) {
        int i = base + j;
        float hc = h[physi(i)];
        if (i > 0 && i + 1 < NL) {
          float hm = h[physi(i - 1)], hp = h[physi(i + 1)];
          if (hm < hc && hc > hp) nUc = i;
          if (hm > hc && hc < hp) nLc = i;
        }
        nreg[j] = ((unsigned)nUc << 16) | (unsigned)nLc;
      }
      sLU[t] = lmU; sLL[t] = lmL; sMx[t] = rmx; sMn[t] = rmn;
      sCU[t] = cU;  sCL[t] = cL;  sNU[t] = nUc; sNL[t] = nLc;
      __syncthreads();
      // Hillis-Steele scans over 512 thread carries (bit-certified vs seq, R5)
      for (int off = 1; off < NT; off <<= 1) {
        int vLU = 0, vLL = 0, vCU = 0, vCL = 0, vNU = 0, vNL = 0;
        float vMx = 0.0f, vMn = 0.0f;
        bool lo = (t >= off), hi = (t + off < NT);
        if (lo) { vLU = sLU[t - off]; vLL = sLL[t - off]; vMx = sMx[t - off];
                  vMn = sMn[t - off]; vCU = sCU[t - off]; vCL = sCL[t - off]; }
        if (hi) { vNU = sNU[t + off]; vNL = sNL[t + off]; }
        __syncthreads();
        if (lo) {
          sLU[t] = max(sLU[t], vLU);  sLL[t] = max(sLL[t], vLL);
          sMx[t] = fmaxf(sMx[t], vMx); sMn[t] = fminf(sMn[t], vMn);
          sCU[t] += vCU; sCL[t] += vCL;
        }
        if (hi) { sNU[t] = min(sNU[t], vNU); sNL[t] = min(sNL[t], vNL); }
        __syncthreads();
      }
      int clU = (t == 0) ? -1 : sLU[t - 1];
      int clL = (t == 0) ? -1 : sLL[t - 1];
      float crx = (t == 0) ? -3.402823466e38f : sMx[t - 1];
      float crn = (t == 0) ? 3.402823466e38f : sMn[t - 1];
      int cnU = (t == NT - 1) ? NL : sNU[t + 1];
      int cnL = (t == NT - 1) ? NL : sNL[t + 1];
      int totU = sCU[NT - 1], totL = sCL[NT - 1];

      // pass C: envelopes + mean — f32 with FUSED interp (XLA-CPU contraction)
      float meanreg[NC];
      double pm2 = 0.0, ph2 = 0.0;
      {
        int lU = clU, lL = clL;
        float rx = crx, rn = crn;
        for (int j = 0; j < NC; j++) {
          int i = base + j;
          float hc = h[physi(i)];
          if (i > 0 && i + 1 < NL) {
            float hm = h[physi(i - 1)], hp = h[physi(i + 1)];
            if (hm < hc && hc > hp) lU = i;
            if (hm > hc && hc < hp) lL = i;
          }
          rx = fmaxf(rx, hc);
          rn = fminf(rn, hc);
          int nUv = (int)(nreg[j] >> 16);     if (cnU < nUv) nUv = cnU;
          int nLv = (int)(nreg[j] & 0xffffu); if (cnL < nLv) nLv = cnL;
          // upper envelope: env = fma(frac, vr-vl, vl)  [single rounding]
          float vl = h[physi(lU < 0 ? 0 : lU)];
          float vr = h[physi(nUv >= NL ? NL - 1 : nUv)];
          int den = nUv - lU;
          float fracU = (float)(i - lU) / (float)(den > 0 ? den : 1);
          float envU = (den > 0) ? __builtin_fmaf(fracU, vr - vl, vl) : vl;
          if (lU < 0) envU = vr;
          if (nUv >= NL) envU = vl;
          if (totU < 2) envU = rx;
          // lower envelope
          float wl = h[physi(lL < 0 ? 0 : lL)];
          float wr = h[physi(nLv >= NL ? NL - 1 : nLv)];
          int den2 = nLv - lL;
          float fracL = (float)(i - lL) / (float)(den2 > 0 ? den2 : 1);
          float envL = (den2 > 0) ? __builtin_fmaf(fracL, wr - wl, wl) : wl;
          if (lL < 0) envL = wr;
          if (nLv >= NL) envL = wl;
          if (totL < 2) envL = rn;
          float mn = 0.5f * (envU + envL);
          meanreg[j] = mn;
          pm2 += (double)mn * (double)mn;    // f32 summands, f64 accumulation
          ph2 += (double)hc * (double)hc;
        }
      }
      double bm2 = blk_reduce_d(pm2, tmp8);
      double bh2 = blk_reduce_d(ph2, tmp8);
      if (t == 0) {
        atomicAdd(&sdsl[(k * N_ITER + it) * 2 + 0], bm2);
        atomicAdd(&sdsl[(k * N_ITER + it) * 2 + 1], bh2);
      }
      // ---- grid barrier ----
      ep++;
      __syncthreads();
      if (t == 0) {
        __hip_atomic_fetch_add(cnt, 1u, __ATOMIC_ACQ_REL, __HIP_MEMORY_SCOPE_AGENT);
        unsigned tgt = ep * gridDim.x;
        while (__hip_atomic_load(cnt, __ATOMIC_ACQUIRE, __HIP_MEMORY_SCOPE_AGENT) < tgt)
          __builtin_amdgcn_s_sleep(2);
        double m2 = __hip_atomic_load(&sdsl[(k * N_ITER + it) * 2 + 0],
                                      __ATOMIC_RELAXED, __HIP_MEMORY_SCOPE_AGENT);
        double h2 = __hip_atomic_load(&sdsl[(k * N_ITER + it) * 2 + 1],
                                      __ATOMIC_RELAXED, __HIP_MEMORY_SCOPE_AGENT);
        sFlag = (m2 / (h2 + 1e-8) < 0.05) ? 1 : 0;
      }
      __syncthreads();
      if (sFlag) break;   // converged: h frozen (JAX done-latch semantics)
      for (int j = 0; j < NC; j++) h[physi(base + j)] -= meanreg[j];
      __syncthreads();
    }

    // ------------- flatness test + outputs (f32 values, f64 sums) -------------
    double s1 = 0.0, s2 = 0.0, s3 = 0.0, s4 = 0.0;  // Σr, Σr², Σd, Σd²
    {
      float rc = res[base] - h[physi(base)];
      for (int j = 0; j < NC; j++) {
        int i = base + j;
        s1 += (double)rc;
        s2 += (double)rc * (double)rc;
        if (i + 1 < NL) {   // within-row diff only
          float rnx = res[i + 1] - h[physi(i + 1)];
          float d = rnx - rc;
          s3 += (double)d;
          s4 += (double)d * (double)d;
          rc = rnx;
        }
      }
    }
    double b1 = blk_reduce_d(s1, tmp8);
    double b2 = blk_reduce_d(s2, tmp8);
    double b3 = blk_reduce_d(s3, tmp8);
    double b4 = blk_reduce_d(s4, tmp8);
    if (t == 0) {
      atomicAdd(&flsl[k * 4 + 0], b1);
      atomicAdd(&flsl[k * 4 + 1], b2);
      atomicAdd(&flsl[k * 4 + 2], b3);
      atomicAdd(&flsl[k * 4 + 3], b4);
    }
    // blk_reduce's syncthreads ordered all cross-thread reads above before these writes
    for (int m = 0; m < NC; m++) {
      int i = m * NT + t;
      float hv = h[physi(i)];
      float r = res[i] - hv;
      outk[i] = hv;        // IMF k
      res[i] = r;          // residual slab of d_out doubles as working res
      h[physi(i)] = r;     // next IMF sifts the residual
    }
    // ---- grid barrier + flatness decision ----
    ep++;
    __syncthreads();
    if (t == 0) {
      __hip_atomic_fetch_add(cnt, 1u, __ATOMIC_ACQ_REL, __HIP_MEMORY_SCOPE_AGENT);
      unsigned tgt = ep * gridDim.x;
      while (__hip_atomic_load(cnt, __ATOMIC_ACQUIRE, __HIP_MEMORY_SCOPE_AGENT) < tgt)
        __builtin_amdgcn_s_sleep(2);
      double S1 = __hip_atomic_load(&flsl[k * 4 + 0], __ATOMIC_RELAXED, __HIP_MEMORY_SCOPE_AGENT);
      double S2 = __hip_atomic_load(&flsl[k * 4 + 1], __ATOMIC_RELAXED, __HIP_MEMORY_SCOPE_AGENT);
      double S3 = __hip_atomic_load(&flsl[k * 4 + 2], __ATOMIC_RELAXED, __HIP_MEMORY_SCOPE_AGENT);
      double S4 = __hip_atomic_load(&flsl[k * 4 + 3], __ATOMIC_RELAXED, __HIP_MEMORY_SCOPE_AGENT);
      double nr = (double)NB * (double)NL;
      double nd = (double)NB * (double)(NL - 1);
      double varr = (S2 - S1 * S1 / nr) / (nr - 1.0);
      double vard = (S4 - S3 * S3 / nd) / (nd - 1.0);
      sFlag = (vard < 0.05 * varr) ? 1 : 0;
    }
    __syncthreads();
    done = done || (sFlag != 0);
  }
}

extern "C" void kernel_launch(void* const* d_in, const int* in_sizes, int n_in,
                              void* d_out, int out_size, void* d_ws, size_t ws_size,
                              hipStream_t stream) {
  const float* x = (const float*)d_in[0];
  float* out = (float*)d_out;
  // ws layout: [0] barrier counter; [256] sd slots (6*12*2 dbl); [1408] flat slots (6*4 dbl)
  size_t zb = ws_size < 4096 ? ws_size : 4096;
  hipMemsetAsync(d_ws, 0, zb, stream);
  unsigned* cnt = (unsigned*)d_ws;
  double* sdsl = (double*)((char*)d_ws + 256);
  double* flsl = (double*)((char*)d_ws + 256 + (size_t)N_IMFS * N_ITER * 2 * 8);
  hipLaunchKernelGGL(emd_main, dim3(NB), dim3(NT), 0, stream, x, out, cnt, sdsl, flsl);
}